// Round 6
// baseline (387.364 us; speedup 1.0000x reference)
//
#include <hip/hip_runtime.h>
#include <hip/hip_bf16.h>
#include <math.h>

#define HIDDEN 1024
#define HEADS 16
#define HEAD_DIM 64
#define POS_DIM 128
#define BATCH 2
#define SEQ 2048
#define TOKENS (BATCH * SEQ)

typedef _Float16 f16;
typedef __attribute__((ext_vector_type(8))) _Float16 f16x8;
typedef __attribute__((ext_vector_type(4))) _Float16 f16x4;
typedef __attribute__((ext_vector_type(4))) float f32x4;

// async global->LDS, 16B per lane; LDS dest = wave-uniform base + lane*16
__device__ __forceinline__ void glds16(const f16* g, f16* l) {
    __builtin_amdgcn_global_load_lds((const __attribute__((address_space(1))) unsigned int*)g,
                                     (__attribute__((address_space(3))) unsigned int*)l, 16, 0, 0);
}

// ---------------------------------------------------------------------------
// cast x (fp32 -> f16), 8 elems/thread
// ---------------------------------------------------------------------------
__global__ __launch_bounds__(256) void cast_x_kernel(const float* __restrict__ x,
                                                     f16* __restrict__ o) {
    const int i = (blockIdx.x * 256 + threadIdx.x) * 8;
    const float4 u = *(const float4*)(x + i);
    const float4 v = *(const float4*)(x + i + 4);
    f16x8 r = {(f16)u.x, (f16)u.y, (f16)u.z, (f16)u.w,
               (f16)v.x, (f16)v.y, (f16)v.z, (f16)v.w};
    *(f16x8*)(o + i) = r;
}

// ---------------------------------------------------------------------------
// 4 weights [1024][1024] fp32 -> Wt f16 transposed, z-indexed (1 launch)
// ---------------------------------------------------------------------------
__global__ __launch_bounds__(256) void cast_wt4_kernel(const float* __restrict__ W0,
                                                       const float* __restrict__ W1,
                                                       const float* __restrict__ W2,
                                                       const float* __restrict__ W3,
                                                       f16* __restrict__ Wt) {
    __shared__ float ts[32][33];
    const int t = threadIdx.x;
    const int z = blockIdx.z;
    const float* W = (z == 0) ? W0 : (z == 1) ? W1 : (z == 2) ? W2 : W3;
    f16* dst = Wt + (size_t)z * HIDDEN * HIDDEN;
    const int k0 = blockIdx.y * 32, n0 = blockIdx.x * 32;
    {
        const int r = t >> 3, c4 = (t & 7) * 4;
        const float4 u = *(const float4*)(W + (size_t)(k0 + r) * HIDDEN + n0 + c4);
        ts[r][c4 + 0] = u.x; ts[r][c4 + 1] = u.y; ts[r][c4 + 2] = u.z; ts[r][c4 + 3] = u.w;
    }
    __syncthreads();
    {
        const int r = t >> 3, c4 = (t & 7) * 4;
        f16* o = dst + (size_t)(n0 + r) * HIDDEN + k0 + c4;
        o[0] = (f16)ts[c4 + 0][r]; o[1] = (f16)ts[c4 + 1][r];
        o[2] = (f16)ts[c4 + 2][r]; o[3] = (f16)ts[c4 + 3][r];
    }
}

// ---------------------------------------------------------------------------
// W1 [1024][128] fp32 -> w1t_hi/lo [128][1024] f16 split (transpose)
// ---------------------------------------------------------------------------
__global__ __launch_bounds__(256) void cast_w1t_kernel(const float* __restrict__ W1,
                                                       f16* __restrict__ Wh,
                                                       f16* __restrict__ Wl) {
    __shared__ float ts[32][33];
    const int t = threadIdx.x;
    const int k0 = blockIdx.y * 32, p0 = blockIdx.x * 32;
    {
        const int r = t >> 3, c4 = (t & 7) * 4;
        const float4 u = *(const float4*)(W1 + (size_t)(k0 + r) * POS_DIM + p0 + c4);
        ts[r][c4 + 0] = u.x; ts[r][c4 + 1] = u.y; ts[r][c4 + 2] = u.z; ts[r][c4 + 3] = u.w;
    }
    __syncthreads();
    {
        const int r = t >> 3, c4 = (t & 7) * 4;
        f16* oh = Wh + (size_t)(p0 + r) * HIDDEN + k0 + c4;
        f16* ol = Wl + (size_t)(p0 + r) * HIDDEN + k0 + c4;
#pragma unroll
        for (int u = 0; u < 4; ++u) {
            const float v = ts[c4 + u][r];
            const f16 hi = (f16)v;
            oh[u] = hi;
            ol[u] = (f16)(v - (float)hi);
        }
    }
}

// ---------------------------------------------------------------------------
// m97-style f16 MFMA GEMM: C[4096][N] = A[4096][1024] @ Bt[N][1024]^T.
// 128x128 tile, BK=64, global_load_lds width-16 staging with XOR k-seg
// swizzle (coalesced global, lane-contiguous LDS, 2-way frag reads).
// ---------------------------------------------------------------------------
__global__ __launch_bounds__(256, 3) void gemm_gll(const f16* __restrict__ A,
                                                   const f16* __restrict__ Bt,
                                                   f16* __restrict__ Cb,
                                                   float* __restrict__ Cf,
                                                   int N, int f16out) {
    __shared__ __align__(16) f16 As[128 * 64];  // [row][slot*8], slot = seg ^ (row&7)
    __shared__ __align__(16) f16 Bs[128 * 64];
    const int tid = threadIdx.x;
    const int w = tid >> 6, lane = tid & 63;
    const int g = lane >> 4, c = lane & 15;
    const int m0 = blockIdx.y * 128, n0 = blockIdx.x * 128;
    const int wm = (w & 1) * 64, wn = (w >> 1) * 64;

    // staging map: wave w covers rows w*32 .. w*32+31 (4 issues of 8 rows)
    const int lrow = lane >> 3;            // 0..7
    const int lseg = (lane & 7) ^ lrow;    // XOR swizzle on global k-segment
    const f16* gA = A + (size_t)(m0 + w * 32 + lrow) * 1024 + lseg * 8;
    const f16* gB = Bt + (size_t)(n0 + w * 32 + lrow) * 1024 + lseg * 8;
    f16* lA = &As[(w * 32) * 64];
    f16* lB = &Bs[(w * 32) * 64];

    f32x4 acc[4][4];
    const f32x4 z = {0.f, 0.f, 0.f, 0.f};
#pragma unroll
    for (int i = 0; i < 4; ++i)
#pragma unroll
        for (int j = 0; j < 4; ++j) acc[i][j] = z;

    const int rsw = c & 7;
    for (int k0 = 0; k0 < 1024; k0 += 64) {
        __syncthreads();   // prior frag reads done
#pragma unroll
        for (int p = 0; p < 4; ++p) {
            glds16(gA + (size_t)p * 8 * 1024 + k0, lA + p * 8 * 64);
            glds16(gB + (size_t)p * 8 * 1024 + k0, lB + p * 8 * 64);
        }
        __syncthreads();   // vmcnt(0) drain: tile visible
#pragma unroll
        for (int s = 0; s < 2; ++s) {
            f16x8 af[4], bf[4];
#pragma unroll
            for (int i = 0; i < 4; ++i)
                af[i] = *(const f16x8*)&As[(wm + i * 16 + c) * 64 + (((s * 4 + g) ^ rsw) * 8)];
#pragma unroll
            for (int j = 0; j < 4; ++j)
                bf[j] = *(const f16x8*)&Bs[(wn + j * 16 + c) * 64 + (((s * 4 + g) ^ rsw) * 8)];
#pragma unroll
            for (int i = 0; i < 4; ++i)
#pragma unroll
                for (int j = 0; j < 4; ++j)
                    acc[i][j] = __builtin_amdgcn_mfma_f32_16x16x32_f16(af[i], bf[j], acc[i][j], 0, 0, 0);
        }
    }
#pragma unroll
    for (int i = 0; i < 4; ++i)
#pragma unroll
        for (int j = 0; j < 4; ++j)
#pragma unroll
            for (int r = 0; r < 4; ++r) {
                const size_t off = (size_t)(m0 + wm + i * 16 + 4 * g + r) * N + n0 + wn + j * 16 + c;
                if (f16out) Cb[off] = (f16)acc[i][j][r];
                else Cf[off] = acc[i][j][r];
            }
}

// ---------------------------------------------------------------------------
// RePo MLP via split-f16 MFMA (unchanged from r5)
// ---------------------------------------------------------------------------
__device__ __forceinline__ float gelu_tanh(float x) {
    const float kA = 0.7978845608028654f;
    return 0.5f * x * (1.0f + tanhf(kA * (x + 0.044715f * x * x * x)));
}

__global__ __launch_bounds__(256, 2) void repo_mfma(const float* __restrict__ x,
                                                    const f16* __restrict__ w1h,
                                                    const f16* __restrict__ w1l,
                                                    const float* __restrict__ b1,
                                                    const float* __restrict__ W2,
                                                    const float* __restrict__ b2,
                                                    float* __restrict__ raw) {
    __shared__ __align__(16) f16 Ash[64 * 32], Asl[64 * 32];
    __shared__ __align__(16) f16 Bsh[128 * 32], Bsl[128 * 32];
    __shared__ float red[4][64];
    const int tid = threadIdx.x;
    const int w = tid >> 6, lane = tid & 63;
    const int g = lane >> 4, c = lane & 15;
    const int m0 = blockIdx.x * 64;

    const int arow = tid >> 2, aseg = tid & 3;
    const int aslot = (aseg ^ ((arow ^ (arow >> 2)) & 3)) << 3;
    const float* gA = x + (size_t)(m0 + arow) * 1024 + aseg * 8;
    const f16* gBh0 = w1h + (size_t)arow * 1024 + aseg * 8;
    const f16* gBh1 = w1h + (size_t)(arow + 64) * 1024 + aseg * 8;
    const f16* gBl0 = w1l + (size_t)arow * 1024 + aseg * 8;
    const f16* gBl1 = w1l + (size_t)(arow + 64) * 1024 + aseg * 8;
    f16* sAh = &Ash[arow * 32 + aslot];
    f16* sAl = &Asl[arow * 32 + aslot];
    f16* sBh0 = &Bsh[arow * 32 + aslot];
    f16* sBh1 = &Bsh[(arow + 64) * 32 + aslot];
    f16* sBl0 = &Bsl[arow * 32 + aslot];
    f16* sBl1 = &Bsl[(arow + 64) * 32 + aslot];

    const int foff = ((g ^ ((c ^ (c >> 2)) & 3)) << 3);

    f32x4 acc[4][2];
    const f32x4 z = {0.f, 0.f, 0.f, 0.f};
#pragma unroll
    for (int i = 0; i < 4; ++i) { acc[i][0] = z; acc[i][1] = z; }

    float4 pa0 = *(const float4*)gA;
    float4 pa1 = *(const float4*)(gA + 4);
    f16x8 pbh0 = *(const f16x8*)gBh0, pbh1 = *(const f16x8*)gBh1;
    f16x8 pbl0 = *(const f16x8*)gBl0, pbl1 = *(const f16x8*)gBl1;

    for (int k0 = 0; k0 < 1024; k0 += 32) {
        __syncthreads();
        {
            const float av[8] = {pa0.x, pa0.y, pa0.z, pa0.w, pa1.x, pa1.y, pa1.z, pa1.w};
            f16x8 ah, al;
#pragma unroll
            for (int u = 0; u < 8; ++u) {
                const f16 hi = (f16)av[u];
                ah[u] = hi;
                al[u] = (f16)(av[u] - (float)hi);
            }
            *(f16x8*)sAh = ah; *(f16x8*)sAl = al;
            *(f16x8*)sBh0 = pbh0; *(f16x8*)sBh1 = pbh1;
            *(f16x8*)sBl0 = pbl0; *(f16x8*)sBl1 = pbl1;
        }
        __syncthreads();
        if (k0 + 32 < 1024) {
            pa0 = *(const float4*)(gA + k0 + 32);
            pa1 = *(const float4*)(gA + k0 + 36);
            pbh0 = *(const f16x8*)(gBh0 + k0 + 32);
            pbh1 = *(const f16x8*)(gBh1 + k0 + 32);
            pbl0 = *(const f16x8*)(gBl0 + k0 + 32);
            pbl1 = *(const f16x8*)(gBl1 + k0 + 32);
        }
        f16x8 ah[4], al[4], bh[2], bl[2];
#pragma unroll
        for (int i = 0; i < 4; ++i) {
            ah[i] = *(const f16x8*)&Ash[(i * 16 + c) * 32 + foff];
            al[i] = *(const f16x8*)&Asl[(i * 16 + c) * 32 + foff];
        }
#pragma unroll
        for (int j = 0; j < 2; ++j) {
            bh[j] = *(const f16x8*)&Bsh[(w * 32 + j * 16 + c) * 32 + foff];
            bl[j] = *(const f16x8*)&Bsl[(w * 32 + j * 16 + c) * 32 + foff];
        }
#pragma unroll
        for (int i = 0; i < 4; ++i)
#pragma unroll
            for (int j = 0; j < 2; ++j) {
                acc[i][j] = __builtin_amdgcn_mfma_f32_16x16x32_f16(ah[i], bh[j], acc[i][j], 0, 0, 0);
                acc[i][j] = __builtin_amdgcn_mfma_f32_16x16x32_f16(ah[i], bl[j], acc[i][j], 0, 0, 0);
                acc[i][j] = __builtin_amdgcn_mfma_f32_16x16x32_f16(al[i], bh[j], acc[i][j], 0, 0, 0);
            }
    }
    float b1v[2], w2v[2];
#pragma unroll
    for (int j = 0; j < 2; ++j) {
        const int col = w * 32 + j * 16 + c;
        b1v[j] = b1[col];
        w2v[j] = W2[col];
    }
    float part[4][4];
#pragma unroll
    for (int i = 0; i < 4; ++i)
#pragma unroll
        for (int r = 0; r < 4; ++r) {
            float s = 0.f;
#pragma unroll
            for (int j = 0; j < 2; ++j)
                s += gelu_tanh(acc[i][j][r] + b1v[j]) * w2v[j];
            s += __shfl_xor(s, 1, 64);
            s += __shfl_xor(s, 2, 64);
            s += __shfl_xor(s, 4, 64);
            s += __shfl_xor(s, 8, 64);
            part[i][r] = s;
        }
    if (c == 0)
#pragma unroll
        for (int i = 0; i < 4; ++i)
#pragma unroll
            for (int r = 0; r < 4; ++r)
                red[w][i * 16 + 4 * g + r] = part[i][r];
    __syncthreads();
    if (tid < 64)
        raw[m0 + tid] = red[0][tid] + red[1][tid] + red[2][tid] + red[3][tid] + b2[0];
}

__device__ __forceinline__ double softplus_d(double x) {
    return (x > 0.0) ? x + log1p(exp(-x)) : log1p(exp(x));
}

__global__ __launch_bounds__(256) void repo_cumsum_kernel(const float* __restrict__ raw,
                                                          float* __restrict__ pos) {
    __shared__ double bufA[256];
    __shared__ double bufB[256];
    const int b = blockIdx.x;
    const int t = threadIdx.x;
    const float* r = raw + (size_t)b * SEQ;

    double loc[8];
    double sum = 0.0;
#pragma unroll
    for (int i = 0; i < 8; ++i) {
        sum += softplus_d((double)r[t * 8 + i]);
        loc[i] = sum;
    }
    bufA[t] = sum;
    __syncthreads();

    double* src = bufA;
    double* dst = bufB;
    for (int off = 1; off < 256; off <<= 1) {
        double v = src[t];
        if (t >= off) v += src[t - off];
        dst[t] = v;
        __syncthreads();
        double* tmp = src; src = dst; dst = tmp;
    }
    const double excl = src[t] - sum;
#pragma unroll
    for (int i = 0; i < 8; ++i)
        pos[(size_t)b * SEQ + t * 8 + i] = (float)(excl + loc[i]);
}

// ---------------------------------------------------------------------------
// cos/sin table [tok][32]
// ---------------------------------------------------------------------------
__global__ __launch_bounds__(256) void sctab_kernel(const float* __restrict__ pos,
                                                    float* __restrict__ costab,
                                                    float* __restrict__ sintab) {
    const int idx = blockIdx.x * 256 + threadIdx.x;
    const int tok = idx >> 5, i = idx & 31;
    const double ang = (double)pos[tok] * exp(-(double)i * 0.28782313662425574);
    double sa, ca;
    sincos(ang, &sa, &ca);
    costab[idx] = (float)ca;
    sintab[idx] = (float)sa;
}

// ---------------------------------------------------------------------------
// Pack K (rope fused) + V into fragment-major layouts; rope Q in-place.
// ---------------------------------------------------------------------------
__global__ __launch_bounds__(256) void packkv_kernel(f16* __restrict__ qkv,
                                                     const float* __restrict__ costab,
                                                     const float* __restrict__ sintab,
                                                     f16* __restrict__ kfo,
                                                     f16* __restrict__ vfo) {
    __shared__ __align__(16) f16 kds[64][72];
    __shared__ __align__(16) f16 vds[64][72];
    const int t = threadIdx.x;
    const int s0 = blockIdx.x * 64;
    const int h = blockIdx.y, b = blockIdx.z;
    const int key = t >> 2, part = t & 3;
    const int tok = b * SEQ + s0 + key;
    {
        float cs[8], sn[8];
        *(float4*)cs       = *(const float4*)(costab + tok * 32 + part * 8);
        *(float4*)(cs + 4) = *(const float4*)(costab + tok * 32 + part * 8 + 4);
        *(float4*)sn       = *(const float4*)(sintab + tok * 32 + part * 8);
        *(float4*)(sn + 4) = *(const float4*)(sintab + tok * 32 + part * 8 + 4);
        // Q rope in place
        f16* qrow = qkv + (size_t)tok * 3072 + h * HEAD_DIM;
        {
            f16x8 lo = *(const f16x8*)(qrow + part * 8);
            f16x8 hi = *(const f16x8*)(qrow + part * 8 + 32);
#pragma unroll
            for (int u = 0; u < 8; ++u) {
                const float l = (float)lo[u], hh = (float)hi[u];
                lo[u] = (f16)(l * cs[u] - hh * sn[u]);
                hi[u] = (f16)(l * sn[u] + hh * cs[u]);
            }
            *(f16x8*)(qrow + part * 8) = lo;
            *(f16x8*)(qrow + part * 8 + 32) = hi;
        }
        // K rope -> LDS
        const f16* krow = qrow + 1024;
        {
            f16x8 lo = *(const f16x8*)(krow + part * 8);
            f16x8 hi = *(const f16x8*)(krow + part * 8 + 32);
#pragma unroll
            for (int u = 0; u < 8; ++u) {
                const float l = (float)lo[u], hh = (float)hi[u];
                kds[key][part * 8 + u]      = (f16)(l * cs[u] - hh * sn[u]);
                kds[key][32 + part * 8 + u] = (f16)(l * sn[u] + hh * cs[u]);
            }
        }
        // V -> transposed LDS
        const f16* vrow = qrow + 2048;
        f16x8 v0 = *(const f16x8*)(vrow + part * 16);
        f16x8 v1 = *(const f16x8*)(vrow + part * 16 + 8);
#pragma unroll
        for (int u = 0; u < 8; ++u) {
            vds[part * 16 + u][key] = v0[u];
            vds[part * 16 + 8 + u][key] = v1[u];
        }
    }
    __syncthreads();
    const size_t cb = ((size_t)((b * HEADS + h) * 32) + blockIdx.x) * 4096;
#pragma unroll
    for (int p = 0; p < 2; ++p) {
        const int idx = p * 256 + t;
        const int frag = idx >> 6, lane = idx & 63;
        const int jn = frag >> 1, half = frag & 1, g = lane >> 4, c = lane & 15;
        *(f16x8*)(kfo + cb + frag * 512 + lane * 8) =
            *(const f16x8*)(&kds[jn * 16 + c][half * 32 + g * 8]);
    }
#pragma unroll
    for (int p = 0; p < 4; ++p) {
        const int idx = p * 256 + t;
        const int frag = idx >> 6, lane = idx & 63;
        const int jd = frag >> 2, jn = frag & 3, g = lane >> 4, c = lane & 15;
        *(f16x4*)(vfo + cb + frag * 256 + lane * 4) =
            *(const f16x4*)(&vds[jd * 16 + c][jn * 16 + 4 * g]);
    }
}

// ---------------------------------------------------------------------------
// MFMA flash attention with split-K(x2): blockIdx.z = b*2 + half, each block
// does 16 of 32 key chunks. Fixed-shift softmax -> partials just add.
// Writes f16 numerator to aof[half] and f32 denom to lsb[half].
// ---------------------------------------------------------------------------
__global__ __launch_bounds__(256, 4) void attn_f16(const f16* __restrict__ qkv,
                                                   const f16* __restrict__ kfr,
                                                   const f16* __restrict__ vfr,
                                                   f16* __restrict__ aof0,
                                                   f16* __restrict__ aof1,
                                                   float* __restrict__ lsb) {
    __shared__ __align__(16) f16 ot[4][32][72];
    const int tid = threadIdx.x;
    const int w = tid >> 6, lane = tid & 63;
    const int g = lane >> 4, c = lane & 15;
    const int h = blockIdx.y;
    const int b = blockIdx.z >> 1, half = blockIdx.z & 1;
    const int bh = b * HEADS + h;
    const int row0 = blockIdx.x * 128 + w * 32;
    const int ch0 = half * 16;

    const f16* qb = qkv + (size_t)(b * SEQ + row0) * 3072 + h * HEAD_DIM + g * 8;
    const f16* kfb = kfr + (size_t)bh * 32 * 4096;
    const f16* vfb = vfr + (size_t)bh * 32 * 4096;

    f16x8 qf[2][2];
#pragma unroll
    for (int i = 0; i < 2; ++i) {
        qf[i][0] = *(const f16x8*)(qb + (size_t)(i * 16 + c) * 3072);
        qf[i][1] = *(const f16x8*)(qb + (size_t)(i * 16 + c) * 3072 + 32);
    }
    const f32x4 z = {0.f, 0.f, 0.f, 0.f};
    f32x4 acc[4][2];
    f32x4 accl[2];
#pragma unroll
    for (int jd = 0; jd < 4; ++jd) { acc[jd][0] = z; acc[jd][1] = z; }
    accl[0] = z; accl[1] = z;

    const f16x4 ones = {(f16)1.f, (f16)1.f, (f16)1.f, (f16)1.f};
    const float SC = 0.125f * 1.4426950408889634f;

    auto loadfr = [&](int ch, f16x8* kf, f16x4* vf) {
        const f16* kp = kfb + (size_t)ch * 4096 + lane * 8;
#pragma unroll
        for (int f = 0; f < 8; ++f) kf[f] = *(const f16x8*)(kp + f * 512);
        const f16* vp = vfb + (size_t)ch * 4096 + lane * 4;
#pragma unroll
        for (int f = 0; f < 16; ++f) vf[f] = *(const f16x4*)(vp + f * 256);
    };
    auto step = [&](const f16x8* kf, const f16x4* vf) {
#pragma unroll
        for (int i = 0; i < 2; ++i) {
            f32x4 s[4];
#pragma unroll
            for (int jn = 0; jn < 4; ++jn) {
                s[jn] = __builtin_amdgcn_mfma_f32_16x16x32_f16(kf[jn * 2], qf[i][0], z, 0, 0, 0);
                s[jn] = __builtin_amdgcn_mfma_f32_16x16x32_f16(kf[jn * 2 + 1], qf[i][1], s[jn], 0, 0, 0);
            }
#pragma unroll
            for (int jn = 0; jn < 4; ++jn) {
                f16x4 pf;
#pragma unroll
                for (int r = 0; r < 4; ++r)
                    pf[r] = (f16)__builtin_amdgcn_exp2f(fmaf(s[jn][r], SC, -8.0f));
                accl[i] = __builtin_amdgcn_mfma_f32_16x16x16f16(ones, pf, accl[i], 0, 0, 0);
#pragma unroll
                for (int jd = 0; jd < 4; ++jd)
                    acc[jd][i] = __builtin_amdgcn_mfma_f32_16x16x16f16(vf[jd * 4 + jn], pf, acc[jd][i], 0, 0, 0);
            }
        }
    };

    f16x8 kA[8], kB[8];
    f16x4 vA[16], vB[16];
    loadfr(ch0, kA, vA);
    for (int ch = 0; ch < 16; ch += 2) {
        loadfr(ch0 + ch + 1, kB, vB);
        step(kA, vA);
        loadfr(ch0 + ((ch + 2) & 15), kA, vA);  // wraps on last iter (unused)
        step(kB, vB);
    }

    // denominators (f32)
    if (lane < 16) {
#pragma unroll
        for (int i = 0; i < 2; ++i)
            lsb[((size_t)(half * 32 + bh)) * SEQ + row0 + i * 16 + lane] = accl[i][0];
    }
    // numerator: O^T regs -> wave-private LDS transpose -> coalesced f16 store
#pragma unroll
    for (int i = 0; i < 2; ++i)
#pragma unroll
        for (int jd = 0; jd < 4; ++jd)
#pragma unroll
            for (int r = 0; r < 4; ++r)
                ot[w][i * 16 + c][jd * 16 + 4 * g + r] = (f16)acc[jd][i][r];
    f16* aofH = half ? aof1 : aof0;
    const int tr = lane >> 1, hf = lane & 1;
    f16* aob = aofH + (size_t)(b * SEQ + row0 + tr) * HIDDEN + h * HEAD_DIM + hf * 32;
#pragma unroll
    for (int q = 0; q < 4; ++q)
        *(f16x8*)(aob + q * 8) = *(const f16x8*)(&ot[w][tr][hf * 32 + q * 8]);
}

// ---------------------------------------------------------------------------
// combine: aof0 = (aof0 + aof1) / (l0 + l1), 8 dims/thread
// ---------------------------------------------------------------------------
__global__ __launch_bounds__(256) void combine_kernel(f16* __restrict__ a0,
                                                      const f16* __restrict__ a1,
                                                      const float* __restrict__ lsb) {
    const int idx = blockIdx.x * 256 + threadIdx.x;   // < TOKENS*128
    const int part = idx & 127;
    const int tok = idx >> 7;
    const int h = part >> 3, d8 = (part & 7) * 8;
    const int b = tok >> 11, s = tok & 2047;
    const size_t li = (size_t)(b * HEADS + h) * SEQ + s;
    const float inv = 1.0f / (lsb[li] + lsb[32 * SEQ + li]);
    const size_t off = (size_t)tok * HIDDEN + h * HEAD_DIM + d8;
    const f16x8 u = *(const f16x8*)(a0 + off);
    const f16x8 v = *(const f16x8*)(a1 + off);
    f16x8 o;
#pragma unroll
    for (int q = 0; q < 8; ++q) o[q] = (f16)(((float)u[q] + (float)v[q]) * inv);
    *(f16x8*)(a0 + off) = o;
}

// ---------------------------------------------------------------------------
// launch
// ---------------------------------------------------------------------------
extern "C" void kernel_launch(void* const* d_in, const int* in_sizes, int n_in,
                              void* d_out, int out_size, void* d_ws, size_t ws_size,
                              hipStream_t stream) {
    const float* x   = (const float*)d_in[0];
    const float* W_q = (const float*)d_in[1];
    const float* W_k = (const float*)d_in[2];
    const float* W_v = (const float*)d_in[3];
    const float* W_o = (const float*)d_in[4];
    const float* rW1 = (const float*)d_in[5];
    const float* rb1 = (const float*)d_in[6];
    const float* rW2 = (const float*)d_in[7];
    const float* rb2 = (const float*)d_in[8];
    float* out = (float*)d_out;

    const size_t MAT = (size_t)TOKENS * HIDDEN;   // 4M
    const size_t WSZ = (size_t)HIDDEN * HIDDEN;   // 1M
    f16* x16  = (f16*)d_ws;
    f16* wqkv = x16 + MAT;            // [3072][1024]; wot contiguous after
    f16* wot  = wqkv + 3 * WSZ;
    f16* qkv  = wot + WSZ;            // [4096][3072]
    f16* kfr  = qkv + 3 * MAT;
    f16* vfr  = kfr + MAT;
    f16* aof0 = vfr + MAT;
    f16* aof1 = aof0 + MAT;
    f16* w1h  = aof1 + MAT;           // [128][1024]
    f16* w1l  = w1h + POS_DIM * HIDDEN;
    float* raw    = (float*)(w1l + POS_DIM * HIDDEN);
    float* pos    = raw + TOKENS;
    float* costab = pos + TOKENS;
    float* sintab = costab + TOKENS * 32;
    float* lsb    = sintab + TOKENS * 32;   // [2][32][2048]

    cast_x_kernel<<<MAT / 2048, 256, 0, stream>>>(x, x16);
    cast_wt4_kernel<<<dim3(32, 32, 4), 256, 0, stream>>>(W_q, W_k, W_v, W_o, wqkv);
    cast_w1t_kernel<<<dim3(4, 32), 256, 0, stream>>>(rW1, w1h, w1l);

    gemm_gll<<<dim3(24, 32), 256, 0, stream>>>(x16, wqkv, qkv, nullptr, 3072, 1);

    repo_mfma<<<64, 256, 0, stream>>>(x, w1h, w1l, rb1, rW2, rb2, raw);
    repo_cumsum_kernel<<<BATCH, 256, 0, stream>>>(raw, pos);
    sctab_kernel<<<TOKENS * 32 / 256, 256, 0, stream>>>(pos, costab, sintab);

    packkv_kernel<<<dim3(SEQ / 64, HEADS, BATCH), 256, 0, stream>>>(qkv, costab, sintab, kfr, vfr);

    attn_f16<<<dim3(SEQ / 128, HEADS, BATCH * 2), 256, 0, stream>>>(qkv, kfr, vfr, aof0, aof1, lsb);
    combine_kernel<<<TOKENS * 128 / 256, 256, 0, stream>>>(aof0, aof1, lsb);

    gemm_gll<<<dim3(8, 32), 256, 0, stream>>>(aof0, wot, nullptr, out, 1024, 0);
}

// Round 7
// 261.781 us; speedup vs baseline: 1.4797x; 1.4797x over previous
//
#include <hip/hip_runtime.h>
#include <hip/hip_bf16.h>
#include <math.h>

#define HIDDEN 1024
#define HEADS 16
#define HEAD_DIM 64
#define POS_DIM 128
#define BATCH 2
#define SEQ 2048
#define TOKENS (BATCH * SEQ)

typedef _Float16 f16;
typedef __attribute__((ext_vector_type(8))) _Float16 f16x8;
typedef __attribute__((ext_vector_type(4))) _Float16 f16x4;
typedef __attribute__((ext_vector_type(4))) float f32x4;

// async global->LDS, 16B per lane; LDS dest = wave-uniform base + lane*16
__device__ __forceinline__ void glds16(const f16* g, f16* l) {
    __builtin_amdgcn_global_load_lds((const __attribute__((address_space(1))) unsigned int*)g,
                                     (__attribute__((address_space(3))) unsigned int*)l, 16, 0, 0);
}

// ---------------------------------------------------------------------------
// cast x (fp32 -> f16), 8 elems/thread
// ---------------------------------------------------------------------------
__global__ __launch_bounds__(256) void cast_x_kernel(const float* __restrict__ x,
                                                     f16* __restrict__ o) {
    const int i = (blockIdx.x * 256 + threadIdx.x) * 8;
    const float4 u = *(const float4*)(x + i);
    const float4 v = *(const float4*)(x + i + 4);
    f16x8 r = {(f16)u.x, (f16)u.y, (f16)u.z, (f16)u.w,
               (f16)v.x, (f16)v.y, (f16)v.z, (f16)v.w};
    *(f16x8*)(o + i) = r;
}

// ---------------------------------------------------------------------------
// 4 weights [1024][1024] fp32 -> Wt f16 transposed, z-indexed (1 launch)
// ---------------------------------------------------------------------------
__global__ __launch_bounds__(256) void cast_wt4_kernel(const float* __restrict__ W0,
                                                       const float* __restrict__ W1,
                                                       const float* __restrict__ W2,
                                                       const float* __restrict__ W3,
                                                       f16* __restrict__ Wt) {
    __shared__ float ts[32][33];
    const int t = threadIdx.x;
    const int z = blockIdx.z;
    const float* W = (z == 0) ? W0 : (z == 1) ? W1 : (z == 2) ? W2 : W3;
    f16* dst = Wt + (size_t)z * HIDDEN * HIDDEN;
    const int k0 = blockIdx.y * 32, n0 = blockIdx.x * 32;
    {
        const int r = t >> 3, c4 = (t & 7) * 4;
        const float4 u = *(const float4*)(W + (size_t)(k0 + r) * HIDDEN + n0 + c4);
        ts[r][c4 + 0] = u.x; ts[r][c4 + 1] = u.y; ts[r][c4 + 2] = u.z; ts[r][c4 + 3] = u.w;
    }
    __syncthreads();
    {
        const int r = t >> 3, c4 = (t & 7) * 4;
        f16* o = dst + (size_t)(n0 + r) * HIDDEN + k0 + c4;
        o[0] = (f16)ts[c4 + 0][r]; o[1] = (f16)ts[c4 + 1][r];
        o[2] = (f16)ts[c4 + 2][r]; o[3] = (f16)ts[c4 + 3][r];
    }
}

// ---------------------------------------------------------------------------
// W1 [1024][128] fp32 -> w1t_hi/lo [128][1024] f16 split (transpose)
// ---------------------------------------------------------------------------
__global__ __launch_bounds__(256) void cast_w1t_kernel(const float* __restrict__ W1,
                                                       f16* __restrict__ Wh,
                                                       f16* __restrict__ Wl) {
    __shared__ float ts[32][33];
    const int t = threadIdx.x;
    const int k0 = blockIdx.y * 32, p0 = blockIdx.x * 32;
    {
        const int r = t >> 3, c4 = (t & 7) * 4;
        const float4 u = *(const float4*)(W1 + (size_t)(k0 + r) * POS_DIM + p0 + c4);
        ts[r][c4 + 0] = u.x; ts[r][c4 + 1] = u.y; ts[r][c4 + 2] = u.z; ts[r][c4 + 3] = u.w;
    }
    __syncthreads();
    {
        const int r = t >> 3, c4 = (t & 7) * 4;
        f16* oh = Wh + (size_t)(p0 + r) * HIDDEN + k0 + c4;
        f16* ol = Wl + (size_t)(p0 + r) * HIDDEN + k0 + c4;
#pragma unroll
        for (int u = 0; u < 4; ++u) {
            const float v = ts[c4 + u][r];
            const f16 hi = (f16)v;
            oh[u] = hi;
            ol[u] = (f16)(v - (float)hi);
        }
    }
}

// ---------------------------------------------------------------------------
// m97-style f16 MFMA GEMM: C[4096][N] = A[4096][1024] @ Bt[N][1024]^T.
// 128x128 tile, BK=64, global_load_lds width-16 staging with XOR k-seg
// swizzle (coalesced global, lane-contiguous LDS, 2-way frag reads).
// ---------------------------------------------------------------------------
__global__ __launch_bounds__(256, 3) void gemm_gll(const f16* __restrict__ A,
                                                   const f16* __restrict__ Bt,
                                                   f16* __restrict__ Cb,
                                                   float* __restrict__ Cf,
                                                   int N, int f16out) {
    __shared__ __align__(16) f16 As[128 * 64];  // [row][slot*8], slot = seg ^ (row&7)
    __shared__ __align__(16) f16 Bs[128 * 64];
    const int tid = threadIdx.x;
    const int w = tid >> 6, lane = tid & 63;
    const int g = lane >> 4, c = lane & 15;
    const int m0 = blockIdx.y * 128, n0 = blockIdx.x * 128;
    const int wm = (w & 1) * 64, wn = (w >> 1) * 64;

    const int lrow = lane >> 3;            // 0..7
    const int lseg = (lane & 7) ^ lrow;    // XOR swizzle on global k-segment
    const f16* gA = A + (size_t)(m0 + w * 32 + lrow) * 1024 + lseg * 8;
    const f16* gB = Bt + (size_t)(n0 + w * 32 + lrow) * 1024 + lseg * 8;
    f16* lA = &As[(w * 32) * 64];
    f16* lB = &Bs[(w * 32) * 64];

    f32x4 acc[4][4];
    const f32x4 z = {0.f, 0.f, 0.f, 0.f};
#pragma unroll
    for (int i = 0; i < 4; ++i)
#pragma unroll
        for (int j = 0; j < 4; ++j) acc[i][j] = z;

    const int rsw = c & 7;
    for (int k0 = 0; k0 < 1024; k0 += 64) {
        __syncthreads();
#pragma unroll
        for (int p = 0; p < 4; ++p) {
            glds16(gA + (size_t)p * 8 * 1024 + k0, lA + p * 8 * 64);
            glds16(gB + (size_t)p * 8 * 1024 + k0, lB + p * 8 * 64);
        }
        __syncthreads();
#pragma unroll
        for (int s = 0; s < 2; ++s) {
            f16x8 af[4], bf[4];
#pragma unroll
            for (int i = 0; i < 4; ++i)
                af[i] = *(const f16x8*)&As[(wm + i * 16 + c) * 64 + (((s * 4 + g) ^ rsw) * 8)];
#pragma unroll
            for (int j = 0; j < 4; ++j)
                bf[j] = *(const f16x8*)&Bs[(wn + j * 16 + c) * 64 + (((s * 4 + g) ^ rsw) * 8)];
#pragma unroll
            for (int i = 0; i < 4; ++i)
#pragma unroll
                for (int j = 0; j < 4; ++j)
                    acc[i][j] = __builtin_amdgcn_mfma_f32_16x16x32_f16(af[i], bf[j], acc[i][j], 0, 0, 0);
        }
    }
#pragma unroll
    for (int i = 0; i < 4; ++i)
#pragma unroll
        for (int j = 0; j < 4; ++j)
#pragma unroll
            for (int r = 0; r < 4; ++r) {
                const size_t off = (size_t)(m0 + wm + i * 16 + 4 * g + r) * N + n0 + wn + j * 16 + c;
                if (f16out) Cb[off] = (f16)acc[i][j][r];
                else Cf[off] = acc[i][j][r];
            }
}

// ---------------------------------------------------------------------------
// RePo MLP via split-f16 MFMA
// ---------------------------------------------------------------------------
__device__ __forceinline__ float gelu_tanh(float x) {
    const float kA = 0.7978845608028654f;
    return 0.5f * x * (1.0f + tanhf(kA * (x + 0.044715f * x * x * x)));
}

__global__ __launch_bounds__(256, 2) void repo_mfma(const float* __restrict__ x,
                                                    const f16* __restrict__ w1h,
                                                    const f16* __restrict__ w1l,
                                                    const float* __restrict__ b1,
                                                    const float* __restrict__ W2,
                                                    const float* __restrict__ b2,
                                                    float* __restrict__ raw) {
    __shared__ __align__(16) f16 Ash[64 * 32], Asl[64 * 32];
    __shared__ __align__(16) f16 Bsh[128 * 32], Bsl[128 * 32];
    __shared__ float red[4][64];
    const int tid = threadIdx.x;
    const int w = tid >> 6, lane = tid & 63;
    const int g = lane >> 4, c = lane & 15;
    const int m0 = blockIdx.x * 64;

    const int arow = tid >> 2, aseg = tid & 3;
    const int aslot = (aseg ^ ((arow ^ (arow >> 2)) & 3)) << 3;
    const float* gA = x + (size_t)(m0 + arow) * 1024 + aseg * 8;
    const f16* gBh0 = w1h + (size_t)arow * 1024 + aseg * 8;
    const f16* gBh1 = w1h + (size_t)(arow + 64) * 1024 + aseg * 8;
    const f16* gBl0 = w1l + (size_t)arow * 1024 + aseg * 8;
    const f16* gBl1 = w1l + (size_t)(arow + 64) * 1024 + aseg * 8;
    f16* sAh = &Ash[arow * 32 + aslot];
    f16* sAl = &Asl[arow * 32 + aslot];
    f16* sBh0 = &Bsh[arow * 32 + aslot];
    f16* sBh1 = &Bsh[(arow + 64) * 32 + aslot];
    f16* sBl0 = &Bsl[arow * 32 + aslot];
    f16* sBl1 = &Bsl[(arow + 64) * 32 + aslot];

    const int foff = ((g ^ ((c ^ (c >> 2)) & 3)) << 3);

    f32x4 acc[4][2];
    const f32x4 z = {0.f, 0.f, 0.f, 0.f};
#pragma unroll
    for (int i = 0; i < 4; ++i) { acc[i][0] = z; acc[i][1] = z; }

    float4 pa0 = *(const float4*)gA;
    float4 pa1 = *(const float4*)(gA + 4);
    f16x8 pbh0 = *(const f16x8*)gBh0, pbh1 = *(const f16x8*)gBh1;
    f16x8 pbl0 = *(const f16x8*)gBl0, pbl1 = *(const f16x8*)gBl1;

    for (int k0 = 0; k0 < 1024; k0 += 32) {
        __syncthreads();
        {
            const float av[8] = {pa0.x, pa0.y, pa0.z, pa0.w, pa1.x, pa1.y, pa1.z, pa1.w};
            f16x8 ah, al;
#pragma unroll
            for (int u = 0; u < 8; ++u) {
                const f16 hi = (f16)av[u];
                ah[u] = hi;
                al[u] = (f16)(av[u] - (float)hi);
            }
            *(f16x8*)sAh = ah; *(f16x8*)sAl = al;
            *(f16x8*)sBh0 = pbh0; *(f16x8*)sBh1 = pbh1;
            *(f16x8*)sBl0 = pbl0; *(f16x8*)sBl1 = pbl1;
        }
        __syncthreads();
        if (k0 + 32 < 1024) {
            pa0 = *(const float4*)(gA + k0 + 32);
            pa1 = *(const float4*)(gA + k0 + 36);
            pbh0 = *(const f16x8*)(gBh0 + k0 + 32);
            pbh1 = *(const f16x8*)(gBh1 + k0 + 32);
            pbl0 = *(const f16x8*)(gBl0 + k0 + 32);
            pbl1 = *(const f16x8*)(gBl1 + k0 + 32);
        }
        f16x8 ah[4], al[4], bh[2], bl[2];
#pragma unroll
        for (int i = 0; i < 4; ++i) {
            ah[i] = *(const f16x8*)&Ash[(i * 16 + c) * 32 + foff];
            al[i] = *(const f16x8*)&Asl[(i * 16 + c) * 32 + foff];
        }
#pragma unroll
        for (int j = 0; j < 2; ++j) {
            bh[j] = *(const f16x8*)&Bsh[(w * 32 + j * 16 + c) * 32 + foff];
            bl[j] = *(const f16x8*)&Bsl[(w * 32 + j * 16 + c) * 32 + foff];
        }
#pragma unroll
        for (int i = 0; i < 4; ++i)
#pragma unroll
            for (int j = 0; j < 2; ++j) {
                acc[i][j] = __builtin_amdgcn_mfma_f32_16x16x32_f16(ah[i], bh[j], acc[i][j], 0, 0, 0);
                acc[i][j] = __builtin_amdgcn_mfma_f32_16x16x32_f16(ah[i], bl[j], acc[i][j], 0, 0, 0);
                acc[i][j] = __builtin_amdgcn_mfma_f32_16x16x32_f16(al[i], bh[j], acc[i][j], 0, 0, 0);
            }
    }
    float b1v[2], w2v[2];
#pragma unroll
    for (int j = 0; j < 2; ++j) {
        const int col = w * 32 + j * 16 + c;
        b1v[j] = b1[col];
        w2v[j] = W2[col];
    }
    float part[4][4];
#pragma unroll
    for (int i = 0; i < 4; ++i)
#pragma unroll
        for (int r = 0; r < 4; ++r) {
            float s = 0.f;
#pragma unroll
            for (int j = 0; j < 2; ++j)
                s += gelu_tanh(acc[i][j][r] + b1v[j]) * w2v[j];
            s += __shfl_xor(s, 1, 64);
            s += __shfl_xor(s, 2, 64);
            s += __shfl_xor(s, 4, 64);
            s += __shfl_xor(s, 8, 64);
            part[i][r] = s;
        }
    if (c == 0)
#pragma unroll
        for (int i = 0; i < 4; ++i)
#pragma unroll
            for (int r = 0; r < 4; ++r)
                red[w][i * 16 + 4 * g + r] = part[i][r];
    __syncthreads();
    if (tid < 64)
        raw[m0 + tid] = red[0][tid] + red[1][tid] + red[2][tid] + red[3][tid] + b2[0];
}

__device__ __forceinline__ double softplus_d(double x) {
    return (x > 0.0) ? x + log1p(exp(-x)) : log1p(exp(x));
}

__global__ __launch_bounds__(256) void repo_cumsum_kernel(const float* __restrict__ raw,
                                                          float* __restrict__ pos) {
    __shared__ double bufA[256];
    __shared__ double bufB[256];
    const int b = blockIdx.x;
    const int t = threadIdx.x;
    const float* r = raw + (size_t)b * SEQ;

    double loc[8];
    double sum = 0.0;
#pragma unroll
    for (int i = 0; i < 8; ++i) {
        sum += softplus_d((double)r[t * 8 + i]);
        loc[i] = sum;
    }
    bufA[t] = sum;
    __syncthreads();

    double* src = bufA;
    double* dst = bufB;
    for (int off = 1; off < 256; off <<= 1) {
        double v = src[t];
        if (t >= off) v += src[t - off];
        dst[t] = v;
        __syncthreads();
        double* tmp = src; src = dst; dst = tmp;
    }
    const double excl = src[t] - sum;
#pragma unroll
    for (int i = 0; i < 8; ++i)
        pos[(size_t)b * SEQ + t * 8 + i] = (float)(excl + loc[i]);
}

// ---------------------------------------------------------------------------
// cos/sin table [tok][32]
// ---------------------------------------------------------------------------
__global__ __launch_bounds__(256) void sctab_kernel(const float* __restrict__ pos,
                                                    float* __restrict__ costab,
                                                    float* __restrict__ sintab) {
    const int idx = blockIdx.x * 256 + threadIdx.x;
    const int tok = idx >> 5, i = idx & 31;
    const double ang = (double)pos[tok] * exp(-(double)i * 0.28782313662425574);
    double sa, ca;
    sincos(ang, &sa, &ca);
    costab[idx] = (float)ca;
    sintab[idx] = (float)sa;
}

// ---------------------------------------------------------------------------
// Pack K (rope fused) + V into fragment-major layouts; rope Q in-place.
// ---------------------------------------------------------------------------
__global__ __launch_bounds__(256) void packkv_kernel(f16* __restrict__ qkv,
                                                     const float* __restrict__ costab,
                                                     const float* __restrict__ sintab,
                                                     f16* __restrict__ kfo,
                                                     f16* __restrict__ vfo) {
    __shared__ __align__(16) f16 kds[64][72];
    __shared__ __align__(16) f16 vds[64][72];
    const int t = threadIdx.x;
    const int s0 = blockIdx.x * 64;
    const int h = blockIdx.y, b = blockIdx.z;
    const int key = t >> 2, part = t & 3;
    const int tok = b * SEQ + s0 + key;
    {
        float cs[8], sn[8];
        *(float4*)cs       = *(const float4*)(costab + tok * 32 + part * 8);
        *(float4*)(cs + 4) = *(const float4*)(costab + tok * 32 + part * 8 + 4);
        *(float4*)sn       = *(const float4*)(sintab + tok * 32 + part * 8);
        *(float4*)(sn + 4) = *(const float4*)(sintab + tok * 32 + part * 8 + 4);
        f16* qrow = qkv + (size_t)tok * 3072 + h * HEAD_DIM;
        {
            f16x8 lo = *(const f16x8*)(qrow + part * 8);
            f16x8 hi = *(const f16x8*)(qrow + part * 8 + 32);
#pragma unroll
            for (int u = 0; u < 8; ++u) {
                const float l = (float)lo[u], hh = (float)hi[u];
                lo[u] = (f16)(l * cs[u] - hh * sn[u]);
                hi[u] = (f16)(l * sn[u] + hh * cs[u]);
            }
            *(f16x8*)(qrow + part * 8) = lo;
            *(f16x8*)(qrow + part * 8 + 32) = hi;
        }
        const f16* krow = qrow + 1024;
        {
            f16x8 lo = *(const f16x8*)(krow + part * 8);
            f16x8 hi = *(const f16x8*)(krow + part * 8 + 32);
#pragma unroll
            for (int u = 0; u < 8; ++u) {
                const float l = (float)lo[u], hh = (float)hi[u];
                kds[key][part * 8 + u]      = (f16)(l * cs[u] - hh * sn[u]);
                kds[key][32 + part * 8 + u] = (f16)(l * sn[u] + hh * cs[u]);
            }
        }
        const f16* vrow = qrow + 2048;
        f16x8 v0 = *(const f16x8*)(vrow + part * 16);
        f16x8 v1 = *(const f16x8*)(vrow + part * 16 + 8);
#pragma unroll
        for (int u = 0; u < 8; ++u) {
            vds[part * 16 + u][key] = v0[u];
            vds[part * 16 + 8 + u][key] = v1[u];
        }
    }
    __syncthreads();
    const size_t cb = ((size_t)((b * HEADS + h) * 32) + blockIdx.x) * 4096;
#pragma unroll
    for (int p = 0; p < 2; ++p) {
        const int idx = p * 256 + t;
        const int frag = idx >> 6, lane = idx & 63;
        const int jn = frag >> 1, half = frag & 1, g = lane >> 4, c = lane & 15;
        *(f16x8*)(kfo + cb + frag * 512 + lane * 8) =
            *(const f16x8*)(&kds[jn * 16 + c][half * 32 + g * 8]);
    }
#pragma unroll
    for (int p = 0; p < 4; ++p) {
        const int idx = p * 256 + t;
        const int frag = idx >> 6, lane = idx & 63;
        const int jd = frag >> 2, jn = frag & 3, g = lane >> 4, c = lane & 15;
        *(f16x4*)(vfo + cb + frag * 256 + lane * 4) =
            *(const f16x4*)(&vds[jd * 16 + c][jn * 16 + 4 * g]);
    }
}

// ---------------------------------------------------------------------------
// MFMA flash attention, split-K(x2). launch_bounds(256,2): cap 256 VGPR so the
// double-buffered frag set (~112 VGPR) does NOT spill (r6 lesson: (256,4)
// forced 64 VGPR -> 368 MB scratch traffic). Occupancy comes from grid=1024.
// ---------------------------------------------------------------------------
__global__ __launch_bounds__(256, 2) void attn_f16(const f16* __restrict__ qkv,
                                                   const f16* __restrict__ kfr,
                                                   const f16* __restrict__ vfr,
                                                   f16* __restrict__ aof0,
                                                   f16* __restrict__ aof1,
                                                   float* __restrict__ lsb) {
    __shared__ __align__(16) f16 ot[4][32][72];
    const int tid = threadIdx.x;
    const int w = tid >> 6, lane = tid & 63;
    const int g = lane >> 4, c = lane & 15;
    const int h = blockIdx.y;
    const int b = blockIdx.z >> 1, half = blockIdx.z & 1;
    const int bh = b * HEADS + h;
    const int row0 = blockIdx.x * 128 + w * 32;
    const int ch0 = half * 16;

    const f16* qb = qkv + (size_t)(b * SEQ + row0) * 3072 + h * HEAD_DIM + g * 8;
    const f16* kfb = kfr + (size_t)bh * 32 * 4096;
    const f16* vfb = vfr + (size_t)bh * 32 * 4096;

    f16x8 qf[2][2];
#pragma unroll
    for (int i = 0; i < 2; ++i) {
        qf[i][0] = *(const f16x8*)(qb + (size_t)(i * 16 + c) * 3072);
        qf[i][1] = *(const f16x8*)(qb + (size_t)(i * 16 + c) * 3072 + 32);
    }
    const f32x4 z = {0.f, 0.f, 0.f, 0.f};
    f32x4 acc[4][2];
    f32x4 accl[2];
#pragma unroll
    for (int jd = 0; jd < 4; ++jd) { acc[jd][0] = z; acc[jd][1] = z; }
    accl[0] = z; accl[1] = z;

    const f16x4 ones = {(f16)1.f, (f16)1.f, (f16)1.f, (f16)1.f};
    const float SC = 0.125f * 1.4426950408889634f;

    auto loadfr = [&](int ch, f16x8* kf, f16x4* vf) {
        const f16* kp = kfb + (size_t)ch * 4096 + lane * 8;
#pragma unroll
        for (int f = 0; f < 8; ++f) kf[f] = *(const f16x8*)(kp + f * 512);
        const f16* vp = vfb + (size_t)ch * 4096 + lane * 4;
#pragma unroll
        for (int f = 0; f < 16; ++f) vf[f] = *(const f16x4*)(vp + f * 256);
    };
    auto step = [&](const f16x8* kf, const f16x4* vf) {
#pragma unroll
        for (int i = 0; i < 2; ++i) {
            f32x4 s[4];
#pragma unroll
            for (int jn = 0; jn < 4; ++jn) {
                s[jn] = __builtin_amdgcn_mfma_f32_16x16x32_f16(kf[jn * 2], qf[i][0], z, 0, 0, 0);
                s[jn] = __builtin_amdgcn_mfma_f32_16x16x32_f16(kf[jn * 2 + 1], qf[i][1], s[jn], 0, 0, 0);
            }
#pragma unroll
            for (int jn = 0; jn < 4; ++jn) {
                f16x4 pf;
#pragma unroll
                for (int r = 0; r < 4; ++r)
                    pf[r] = (f16)__builtin_amdgcn_exp2f(fmaf(s[jn][r], SC, -8.0f));
                accl[i] = __builtin_amdgcn_mfma_f32_16x16x16f16(ones, pf, accl[i], 0, 0, 0);
#pragma unroll
                for (int jd = 0; jd < 4; ++jd)
                    acc[jd][i] = __builtin_amdgcn_mfma_f32_16x16x16f16(vf[jd * 4 + jn], pf, acc[jd][i], 0, 0, 0);
            }
        }
    };

    f16x8 kA[8], kB[8];
    f16x4 vA[16], vB[16];
    loadfr(ch0, kA, vA);
    for (int ch = 0; ch < 16; ch += 2) {
        loadfr(ch0 + ch + 1, kB, vB);
        step(kA, vA);
        loadfr(ch0 + ((ch + 2) & 15), kA, vA);  // wraps on last iter (unused)
        step(kB, vB);
    }

    // denominators (f32)
    if (lane < 16) {
#pragma unroll
        for (int i = 0; i < 2; ++i)
            lsb[((size_t)(half * 32 + bh)) * SEQ + row0 + i * 16 + lane] = accl[i][0];
    }
    // numerator: O^T regs -> wave-private LDS transpose -> coalesced f16 store
#pragma unroll
    for (int i = 0; i < 2; ++i)
#pragma unroll
        for (int jd = 0; jd < 4; ++jd)
#pragma unroll
            for (int r = 0; r < 4; ++r)
                ot[w][i * 16 + c][jd * 16 + 4 * g + r] = (f16)acc[jd][i][r];
    f16* aofH = half ? aof1 : aof0;
    const int tr = lane >> 1, hf = lane & 1;
    f16* aob = aofH + (size_t)(b * SEQ + row0 + tr) * HIDDEN + h * HEAD_DIM + hf * 32;
#pragma unroll
    for (int q = 0; q < 4; ++q)
        *(f16x8*)(aob + q * 8) = *(const f16x8*)(&ot[w][tr][hf * 32 + q * 8]);
}

// ---------------------------------------------------------------------------
// combine: aof0 = (aof0 + aof1) / (l0 + l1), 8 dims/thread
// ---------------------------------------------------------------------------
__global__ __launch_bounds__(256) void combine_kernel(f16* __restrict__ a0,
                                                      const f16* __restrict__ a1,
                                                      const float* __restrict__ lsb) {
    const int idx = blockIdx.x * 256 + threadIdx.x;   // < TOKENS*128
    const int part = idx & 127;
    const int tok = idx >> 7;
    const int h = part >> 3, d8 = (part & 7) * 8;
    const int b = tok >> 11, s = tok & 2047;
    const size_t li = (size_t)(b * HEADS + h) * SEQ + s;
    const float inv = 1.0f / (lsb[li] + lsb[32 * SEQ + li]);
    const size_t off = (size_t)tok * HIDDEN + h * HEAD_DIM + d8;
    const f16x8 u = *(const f16x8*)(a0 + off);
    const f16x8 v = *(const f16x8*)(a1 + off);
    f16x8 o;
#pragma unroll
    for (int q = 0; q < 8; ++q) o[q] = (f16)(((float)u[q] + (float)v[q]) * inv);
    *(f16x8*)(a0 + off) = o;
}

// ---------------------------------------------------------------------------
// launch
// ---------------------------------------------------------------------------
extern "C" void kernel_launch(void* const* d_in, const int* in_sizes, int n_in,
                              void* d_out, int out_size, void* d_ws, size_t ws_size,
                              hipStream_t stream) {
    const float* x   = (const float*)d_in[0];
    const float* W_q = (const float*)d_in[1];
    const float* W_k = (const float*)d_in[2];
    const float* W_v = (const float*)d_in[3];
    const float* W_o = (const float*)d_in[4];
    const float* rW1 = (const float*)d_in[5];
    const float* rb1 = (const float*)d_in[6];
    const float* rW2 = (const float*)d_in[7];
    const float* rb2 = (const float*)d_in[8];
    float* out = (float*)d_out;

    const size_t MAT = (size_t)TOKENS * HIDDEN;   // 4M
    const size_t WSZ = (size_t)HIDDEN * HIDDEN;   // 1M
    f16* x16  = (f16*)d_ws;
    f16* wqkv = x16 + MAT;            // [3072][1024]; wot contiguous after
    f16* wot  = wqkv + 3 * WSZ;
    f16* qkv  = wot + WSZ;            // [4096][3072]
    f16* kfr  = qkv + 3 * MAT;
    f16* vfr  = kfr + MAT;
    f16* aof0 = vfr + MAT;
    f16* aof1 = aof0 + MAT;
    f16* w1h  = aof1 + MAT;           // [128][1024]
    f16* w1l  = w1h + POS_DIM * HIDDEN;
    float* raw    = (float*)(w1l + POS_DIM * HIDDEN);
    float* pos    = raw + TOKENS;
    float* costab = pos + TOKENS;
    float* sintab = costab + TOKENS * 32;
    float* lsb    = sintab + TOKENS * 32;   // [2][32][2048]

    cast_x_kernel<<<MAT / 2048, 256, 0, stream>>>(x, x16);
    cast_wt4_kernel<<<dim3(32, 32, 4), 256, 0, stream>>>(W_q, W_k, W_v, W_o, wqkv);
    cast_w1t_kernel<<<dim3(4, 32), 256, 0, stream>>>(rW1, w1h, w1l);

    gemm_gll<<<dim3(24, 32), 256, 0, stream>>>(x16, wqkv, qkv, nullptr, 3072, 1);

    repo_mfma<<<64, 256, 0, stream>>>(x, w1h, w1l, rb1, rW2, rb2, raw);
    repo_cumsum_kernel<<<BATCH, 256, 0, stream>>>(raw, pos);
    sctab_kernel<<<TOKENS * 32 / 256, 256, 0, stream>>>(pos, costab, sintab);

    packkv_kernel<<<dim3(SEQ / 64, HEADS, BATCH), 256, 0, stream>>>(qkv, costab, sintab, kfr, vfr);

    attn_f16<<<dim3(SEQ / 128, HEADS, BATCH * 2), 256, 0, stream>>>(qkv, kfr, vfr, aof0, aof1, lsb);
    combine_kernel<<<TOKENS * 128 / 256, 256, 0, stream>>>(aof0, aof1, lsb);

    gemm_gll<<<dim3(8, 32), 256, 0, stream>>>(aof0, wot, nullptr, out, 1024, 0);
}

// Round 9
// 250.361 us; speedup vs baseline: 1.5472x; 1.0456x over previous
//
#include <hip/hip_runtime.h>
#include <hip/hip_bf16.h>
#include <math.h>

#define HIDDEN 1024
#define HEADS 16
#define HEAD_DIM 64
#define POS_DIM 128
#define BATCH 2
#define SEQ 2048
#define TOKENS (BATCH * SEQ)

typedef _Float16 f16;
typedef __attribute__((ext_vector_type(8))) _Float16 f16x8;
typedef __attribute__((ext_vector_type(4))) _Float16 f16x4;
typedef __attribute__((ext_vector_type(4))) float f32x4;

// async global->LDS, 16B per lane; LDS dest = wave-uniform base + lane*16
__device__ __forceinline__ void glds16(const f16* g, f16* l) {
    __builtin_amdgcn_global_load_lds((const __attribute__((address_space(1))) unsigned int*)g,
                                     (__attribute__((address_space(3))) unsigned int*)l, 16, 0, 0);
}

// ---------------------------------------------------------------------------
// cast x (fp32 -> f16), 8 elems/thread
// ---------------------------------------------------------------------------
__global__ __launch_bounds__(256) void cast_x_kernel(const float* __restrict__ x,
                                                     f16* __restrict__ o) {
    const int i = (blockIdx.x * 256 + threadIdx.x) * 8;
    const float4 u = *(const float4*)(x + i);
    const float4 v = *(const float4*)(x + i + 4);
    f16x8 r = {(f16)u.x, (f16)u.y, (f16)u.z, (f16)u.w,
               (f16)v.x, (f16)v.y, (f16)v.z, (f16)v.w};
    *(f16x8*)(o + i) = r;
}

// ---------------------------------------------------------------------------
// 4 weights [1024][1024] fp32 -> Wt f16 transposed, z-indexed (1 launch)
// ---------------------------------------------------------------------------
__global__ __launch_bounds__(256) void cast_wt4_kernel(const float* __restrict__ W0,
                                                       const float* __restrict__ W1,
                                                       const float* __restrict__ W2,
                                                       const float* __restrict__ W3,
                                                       f16* __restrict__ Wt) {
    __shared__ float ts[32][33];
    const int t = threadIdx.x;
    const int z = blockIdx.z;
    const float* W = (z == 0) ? W0 : (z == 1) ? W1 : (z == 2) ? W2 : W3;
    f16* dst = Wt + (size_t)z * HIDDEN * HIDDEN;
    const int k0 = blockIdx.y * 32, n0 = blockIdx.x * 32;
    {
        const int r = t >> 3, c4 = (t & 7) * 4;
        const float4 u = *(const float4*)(W + (size_t)(k0 + r) * HIDDEN + n0 + c4);
        ts[r][c4 + 0] = u.x; ts[r][c4 + 1] = u.y; ts[r][c4 + 2] = u.z; ts[r][c4 + 3] = u.w;
    }
    __syncthreads();
    {
        const int r = t >> 3, c4 = (t & 7) * 4;
        f16* o = dst + (size_t)(n0 + r) * HIDDEN + k0 + c4;
        o[0] = (f16)ts[c4 + 0][r]; o[1] = (f16)ts[c4 + 1][r];
        o[2] = (f16)ts[c4 + 2][r]; o[3] = (f16)ts[c4 + 3][r];
    }
}

// ---------------------------------------------------------------------------
// W1 [1024][128] fp32 -> w1t_hi/lo [128][1024] f16 split (transpose)
// ---------------------------------------------------------------------------
__global__ __launch_bounds__(256) void cast_w1t_kernel(const float* __restrict__ W1,
                                                       f16* __restrict__ Wh,
                                                       f16* __restrict__ Wl) {
    __shared__ float ts[32][33];
    const int t = threadIdx.x;
    const int k0 = blockIdx.y * 32, p0 = blockIdx.x * 32;
    {
        const int r = t >> 3, c4 = (t & 7) * 4;
        const float4 u = *(const float4*)(W1 + (size_t)(k0 + r) * POS_DIM + p0 + c4);
        ts[r][c4 + 0] = u.x; ts[r][c4 + 1] = u.y; ts[r][c4 + 2] = u.z; ts[r][c4 + 3] = u.w;
    }
    __syncthreads();
    {
        const int r = t >> 3, c4 = (t & 7) * 4;
        f16* oh = Wh + (size_t)(p0 + r) * HIDDEN + k0 + c4;
        f16* ol = Wl + (size_t)(p0 + r) * HIDDEN + k0 + c4;
#pragma unroll
        for (int u = 0; u < 4; ++u) {
            const float v = ts[c4 + u][r];
            const f16 hi = (f16)v;
            oh[u] = hi;
            ol[u] = (f16)(v - (float)hi);
        }
    }
}

// ---------------------------------------------------------------------------
// m97-style f16 MFMA GEMM: C[4096][N] = A[4096][1024] @ Bt[N][1024]^T.
// ---------------------------------------------------------------------------
__global__ __launch_bounds__(256, 3) void gemm_gll(const f16* __restrict__ A,
                                                   const f16* __restrict__ Bt,
                                                   f16* __restrict__ Cb,
                                                   float* __restrict__ Cf,
                                                   int N, int f16out) {
    __shared__ __align__(16) f16 As[128 * 64];  // [row][slot*8], slot = seg ^ (row&7)
    __shared__ __align__(16) f16 Bs[128 * 64];
    const int tid = threadIdx.x;
    const int w = tid >> 6, lane = tid & 63;
    const int g = lane >> 4, c = lane & 15;
    const int m0 = blockIdx.y * 128, n0 = blockIdx.x * 128;
    const int wm = (w & 1) * 64, wn = (w >> 1) * 64;

    const int lrow = lane >> 3;            // 0..7
    const int lseg = (lane & 7) ^ lrow;    // XOR swizzle on global k-segment
    const f16* gA = A + (size_t)(m0 + w * 32 + lrow) * 1024 + lseg * 8;
    const f16* gB = Bt + (size_t)(n0 + w * 32 + lrow) * 1024 + lseg * 8;
    f16* lA = &As[(w * 32) * 64];
    f16* lB = &Bs[(w * 32) * 64];

    f32x4 acc[4][4];
    const f32x4 z = {0.f, 0.f, 0.f, 0.f};
#pragma unroll
    for (int i = 0; i < 4; ++i)
#pragma unroll
        for (int j = 0; j < 4; ++j) acc[i][j] = z;

    const int rsw = c & 7;
    for (int k0 = 0; k0 < 1024; k0 += 64) {
        __syncthreads();
#pragma unroll
        for (int p = 0; p < 4; ++p) {
            glds16(gA + (size_t)p * 8 * 1024 + k0, lA + p * 8 * 64);
            glds16(gB + (size_t)p * 8 * 1024 + k0, lB + p * 8 * 64);
        }
        __syncthreads();
#pragma unroll
        for (int s = 0; s < 2; ++s) {
            f16x8 af[4], bf[4];
#pragma unroll
            for (int i = 0; i < 4; ++i)
                af[i] = *(const f16x8*)&As[(wm + i * 16 + c) * 64 + (((s * 4 + g) ^ rsw) * 8)];
#pragma unroll
            for (int j = 0; j < 4; ++j)
                bf[j] = *(const f16x8*)&Bs[(wn + j * 16 + c) * 64 + (((s * 4 + g) ^ rsw) * 8)];
#pragma unroll
            for (int i = 0; i < 4; ++i)
#pragma unroll
                for (int j = 0; j < 4; ++j)
                    acc[i][j] = __builtin_amdgcn_mfma_f32_16x16x32_f16(af[i], bf[j], acc[i][j], 0, 0, 0);
        }
    }
#pragma unroll
    for (int i = 0; i < 4; ++i)
#pragma unroll
        for (int j = 0; j < 4; ++j)
#pragma unroll
            for (int r = 0; r < 4; ++r) {
                const size_t off = (size_t)(m0 + wm + i * 16 + 4 * g + r) * N + n0 + wn + j * 16 + c;
                if (f16out) Cb[off] = (f16)acc[i][j][r];
                else Cf[off] = acc[i][j][r];
            }
}

// ---------------------------------------------------------------------------
// RePo MLP via split-f16 MFMA
// ---------------------------------------------------------------------------
__device__ __forceinline__ float gelu_tanh(float x) {
    const float kA = 0.7978845608028654f;
    return 0.5f * x * (1.0f + tanhf(kA * (x + 0.044715f * x * x * x)));
}

__global__ __launch_bounds__(256, 2) void repo_mfma(const float* __restrict__ x,
                                                    const f16* __restrict__ w1h,
                                                    const f16* __restrict__ w1l,
                                                    const float* __restrict__ b1,
                                                    const float* __restrict__ W2,
                                                    const float* __restrict__ b2,
                                                    float* __restrict__ raw) {
    __shared__ __align__(16) f16 Ash[64 * 32], Asl[64 * 32];
    __shared__ __align__(16) f16 Bsh[128 * 32], Bsl[128 * 32];
    __shared__ float red[4][64];
    const int tid = threadIdx.x;
    const int w = tid >> 6, lane = tid & 63;
    const int g = lane >> 4, c = lane & 15;
    const int m0 = blockIdx.x * 64;

    const int arow = tid >> 2, aseg = tid & 3;
    const int aslot = (aseg ^ ((arow ^ (arow >> 2)) & 3)) << 3;
    const float* gA = x + (size_t)(m0 + arow) * 1024 + aseg * 8;
    const f16* gBh0 = w1h + (size_t)arow * 1024 + aseg * 8;
    const f16* gBh1 = w1h + (size_t)(arow + 64) * 1024 + aseg * 8;
    const f16* gBl0 = w1l + (size_t)arow * 1024 + aseg * 8;
    const f16* gBl1 = w1l + (size_t)(arow + 64) * 1024 + aseg * 8;
    f16* sAh = &Ash[arow * 32 + aslot];
    f16* sAl = &Asl[arow * 32 + aslot];
    f16* sBh0 = &Bsh[arow * 32 + aslot];
    f16* sBh1 = &Bsh[(arow + 64) * 32 + aslot];
    f16* sBl0 = &Bsl[arow * 32 + aslot];
    f16* sBl1 = &Bsl[(arow + 64) * 32 + aslot];

    const int foff = ((g ^ ((c ^ (c >> 2)) & 3)) << 3);

    f32x4 acc[4][2];
    const f32x4 z = {0.f, 0.f, 0.f, 0.f};
#pragma unroll
    for (int i = 0; i < 4; ++i) { acc[i][0] = z; acc[i][1] = z; }

    float4 pa0 = *(const float4*)gA;
    float4 pa1 = *(const float4*)(gA + 4);
    f16x8 pbh0 = *(const f16x8*)gBh0, pbh1 = *(const f16x8*)gBh1;
    f16x8 pbl0 = *(const f16x8*)gBl0, pbl1 = *(const f16x8*)gBl1;

    for (int k0 = 0; k0 < 1024; k0 += 32) {
        __syncthreads();
        {
            const float av[8] = {pa0.x, pa0.y, pa0.z, pa0.w, pa1.x, pa1.y, pa1.z, pa1.w};
            f16x8 ah, al;
#pragma unroll
            for (int u = 0; u < 8; ++u) {
                const f16 hi = (f16)av[u];
                ah[u] = hi;
                al[u] = (f16)(av[u] - (float)hi);
            }
            *(f16x8*)sAh = ah; *(f16x8*)sAl = al;
            *(f16x8*)sBh0 = pbh0; *(f16x8*)sBh1 = pbh1;
            *(f16x8*)sBl0 = pbl0; *(f16x8*)sBl1 = pbl1;
        }
        __syncthreads();
        if (k0 + 32 < 1024) {
            pa0 = *(const float4*)(gA + k0 + 32);
            pa1 = *(const float4*)(gA + k0 + 36);
            pbh0 = *(const f16x8*)(gBh0 + k0 + 32);
            pbh1 = *(const f16x8*)(gBh1 + k0 + 32);
            pbl0 = *(const f16x8*)(gBl0 + k0 + 32);
            pbl1 = *(const f16x8*)(gBl1 + k0 + 32);
        }
        f16x8 ah[4], al[4], bh[2], bl[2];
#pragma unroll
        for (int i = 0; i < 4; ++i) {
            ah[i] = *(const f16x8*)&Ash[(i * 16 + c) * 32 + foff];
            al[i] = *(const f16x8*)&Asl[(i * 16 + c) * 32 + foff];
        }
#pragma unroll
        for (int j = 0; j < 2; ++j) {
            bh[j] = *(const f16x8*)&Bsh[(w * 32 + j * 16 + c) * 32 + foff];
            bl[j] = *(const f16x8*)&Bsl[(w * 32 + j * 16 + c) * 32 + foff];
        }
#pragma unroll
        for (int i = 0; i < 4; ++i)
#pragma unroll
            for (int j = 0; j < 2; ++j) {
                acc[i][j] = __builtin_amdgcn_mfma_f32_16x16x32_f16(ah[i], bh[j], acc[i][j], 0, 0, 0);
                acc[i][j] = __builtin_amdgcn_mfma_f32_16x16x32_f16(ah[i], bl[j], acc[i][j], 0, 0, 0);
                acc[i][j] = __builtin_amdgcn_mfma_f32_16x16x32_f16(al[i], bh[j], acc[i][j], 0, 0, 0);
            }
    }
    float b1v[2], w2v[2];
#pragma unroll
    for (int j = 0; j < 2; ++j) {
        const int col = w * 32 + j * 16 + c;
        b1v[j] = b1[col];
        w2v[j] = W2[col];
    }
    float part[4][4];
#pragma unroll
    for (int i = 0; i < 4; ++i)
#pragma unroll
        for (int r = 0; r < 4; ++r) {
            float s = 0.f;
#pragma unroll
            for (int j = 0; j < 2; ++j)
                s += gelu_tanh(acc[i][j][r] + b1v[j]) * w2v[j];
            s += __shfl_xor(s, 1, 64);
            s += __shfl_xor(s, 2, 64);
            s += __shfl_xor(s, 4, 64);
            s += __shfl_xor(s, 8, 64);
            part[i][r] = s;
        }
    if (c == 0)
#pragma unroll
        for (int i = 0; i < 4; ++i)
#pragma unroll
            for (int r = 0; r < 4; ++r)
                red[w][i * 16 + 4 * g + r] = part[i][r];
    __syncthreads();
    if (tid < 64)
        raw[m0 + tid] = red[0][tid] + red[1][tid] + red[2][tid] + red[3][tid] + b2[0];
}

__device__ __forceinline__ double softplus_d(double x) {
    return (x > 0.0) ? x + log1p(exp(-x)) : log1p(exp(x));
}

__global__ __launch_bounds__(256) void repo_cumsum_kernel(const float* __restrict__ raw,
                                                          float* __restrict__ pos) {
    __shared__ double bufA[256];
    __shared__ double bufB[256];
    const int b = blockIdx.x;
    const int t = threadIdx.x;
    const float* r = raw + (size_t)b * SEQ;

    double loc[8];
    double sum = 0.0;
#pragma unroll
    for (int i = 0; i < 8; ++i) {
        sum += softplus_d((double)r[t * 8 + i]);
        loc[i] = sum;
    }
    bufA[t] = sum;
    __syncthreads();

    double* src = bufA;
    double* dst = bufB;
    for (int off = 1; off < 256; off <<= 1) {
        double v = src[t];
        if (t >= off) v += src[t - off];
        dst[t] = v;
        __syncthreads();
        double* tmp = src; src = dst; dst = tmp;
    }
    const double excl = src[t] - sum;
#pragma unroll
    for (int i = 0; i < 8; ++i)
        pos[(size_t)b * SEQ + t * 8 + i] = (float)(excl + loc[i]);
}

// ---------------------------------------------------------------------------
// cos/sin table [tok][32]
// ---------------------------------------------------------------------------
__global__ __launch_bounds__(256) void sctab_kernel(const float* __restrict__ pos,
                                                    float* __restrict__ costab,
                                                    float* __restrict__ sintab) {
    const int idx = blockIdx.x * 256 + threadIdx.x;
    const int tok = idx >> 5, i = idx & 31;
    const double ang = (double)pos[tok] * exp(-(double)i * 0.28782313662425574);
    double sa, ca;
    sincos(ang, &sa, &ca);
    costab[idx] = (float)ca;
    sintab[idx] = (float)sa;
}

// ---------------------------------------------------------------------------
// Pack K (rope fused) + V into fragment-major layouts; rope Q in-place.
// (exactly the r7 layouts: K frag f16x8 at frag*512+lane*8; V frag f16x4 at
//  frag*256+lane*4)
// ---------------------------------------------------------------------------
__global__ __launch_bounds__(256) void packkv_kernel(f16* __restrict__ qkv,
                                                     const float* __restrict__ costab,
                                                     const float* __restrict__ sintab,
                                                     f16* __restrict__ kfo,
                                                     f16* __restrict__ vfo) {
    __shared__ __align__(16) f16 kds[64][72];
    __shared__ __align__(16) f16 vds[64][72];
    const int t = threadIdx.x;
    const int s0 = blockIdx.x * 64;
    const int h = blockIdx.y, b = blockIdx.z;
    const int key = t >> 2, part = t & 3;
    const int tok = b * SEQ + s0 + key;
    {
        float cs[8], sn[8];
        *(float4*)cs       = *(const float4*)(costab + tok * 32 + part * 8);
        *(float4*)(cs + 4) = *(const float4*)(costab + tok * 32 + part * 8 + 4);
        *(float4*)sn       = *(const float4*)(sintab + tok * 32 + part * 8);
        *(float4*)(sn + 4) = *(const float4*)(sintab + tok * 32 + part * 8 + 4);
        f16* qrow = qkv + (size_t)tok * 3072 + h * HEAD_DIM;
        {
            f16x8 lo = *(const f16x8*)(qrow + part * 8);
            f16x8 hi = *(const f16x8*)(qrow + part * 8 + 32);
#pragma unroll
            for (int u = 0; u < 8; ++u) {
                const float l = (float)lo[u], hh = (float)hi[u];
                lo[u] = (f16)(l * cs[u] - hh * sn[u]);
                hi[u] = (f16)(l * sn[u] + hh * cs[u]);
            }
            *(f16x8*)(qrow + part * 8) = lo;
            *(f16x8*)(qrow + part * 8 + 32) = hi;
        }
        const f16* krow = qrow + 1024;
        {
            f16x8 lo = *(const f16x8*)(krow + part * 8);
            f16x8 hi = *(const f16x8*)(krow + part * 8 + 32);
#pragma unroll
            for (int u = 0; u < 8; ++u) {
                const float l = (float)lo[u], hh = (float)hi[u];
                kds[key][part * 8 + u]      = (f16)(l * cs[u] - hh * sn[u]);
                kds[key][32 + part * 8 + u] = (f16)(l * sn[u] + hh * cs[u]);
            }
        }
        const f16* vrow = qrow + 2048;
        f16x8 v0 = *(const f16x8*)(vrow + part * 16);
        f16x8 v1 = *(const f16x8*)(vrow + part * 16 + 8);
#pragma unroll
        for (int u = 0; u < 8; ++u) {
            vds[part * 16 + u][key] = v0[u];
            vds[part * 16 + 8 + u][key] = v1[u];
        }
    }
    __syncthreads();
    const size_t cb = ((size_t)((b * HEADS + h) * 32) + blockIdx.x) * 4096;
#pragma unroll
    for (int p = 0; p < 2; ++p) {
        const int idx = p * 256 + t;
        const int frag = idx >> 6, lane = idx & 63;
        const int jn = frag >> 1, half = frag & 1, g = lane >> 4, c = lane & 15;
        *(f16x8*)(kfo + cb + frag * 512 + lane * 8) =
            *(const f16x8*)(&kds[jn * 16 + c][half * 32 + g * 8]);
    }
#pragma unroll
    for (int p = 0; p < 4; ++p) {
        const int idx = p * 256 + t;
        const int frag = idx >> 6, lane = idx & 63;
        const int jd = frag >> 2, jn = frag & 3, g = lane >> 4, c = lane & 15;
        *(f16x4*)(vfo + cb + frag * 256 + lane * 4) =
            *(const f16x4*)(&vds[jd * 16 + c][jn * 16 + 4 * g]);
    }
}

// ---------------------------------------------------------------------------
// MFMA flash attention, split-K(x2). K/V staged per-BLOCK into LDS via glds16
// using the PROVEN gemm_gll discipline: single buffer, barrier -> stage ->
// barrier -> ds_read. Fragment math byte-identical to r7 (which passed).
// Single frag set (64 VGPR, was 128 double-buffered) -> higher occupancy.
// ot kept as separate LDS (NO aliasing with staging - r8 lesson).
// ---------------------------------------------------------------------------
__global__ __launch_bounds__(256, 2) void attn_f16(const f16* __restrict__ qkv,
                                                   const f16* __restrict__ kfr,
                                                   const f16* __restrict__ vfr,
                                                   f16* __restrict__ aof0,
                                                   f16* __restrict__ aof1,
                                                   float* __restrict__ lsb) {
    __shared__ __align__(16) f16 kls[4096];     // one K chunk (8 KB)
    __shared__ __align__(16) f16 vls[4096];     // one V chunk (8 KB)
    __shared__ __align__(16) f16 ot[4][32][72]; // epilogue transpose (18 KB)
    const int tid = threadIdx.x;
    const int w = tid >> 6, lane = tid & 63;
    const int g = lane >> 4, c = lane & 15;
    const int h = blockIdx.y;
    const int b = blockIdx.z >> 1, half = blockIdx.z & 1;
    const int bh = b * HEADS + h;
    const int row0 = blockIdx.x * 128 + w * 32;
    const int ch0 = half * 16;

    const f16* qb = qkv + (size_t)(b * SEQ + row0) * 3072 + h * HEAD_DIM + g * 8;
    const f16* kfb = kfr + (size_t)bh * 32 * 4096;
    const f16* vfb = vfr + (size_t)bh * 32 * 4096;

    f16x8 qf[2][2];
#pragma unroll
    for (int i = 0; i < 2; ++i) {
        qf[i][0] = *(const f16x8*)(qb + (size_t)(i * 16 + c) * 3072);
        qf[i][1] = *(const f16x8*)(qb + (size_t)(i * 16 + c) * 3072 + 32);
    }
    const f32x4 z = {0.f, 0.f, 0.f, 0.f};
    f32x4 acc[4][2];
    f32x4 accl[2];
#pragma unroll
    for (int jd = 0; jd < 4; ++jd) { acc[jd][0] = z; acc[jd][1] = z; }
    accl[0] = z; accl[1] = z;

    const f16x4 ones = {(f16)1.f, (f16)1.f, (f16)1.f, (f16)1.f};
    const float SC = 0.125f * 1.4426950408889634f;

    for (int cc = 0; cc < 16; ++cc) {
        const int ch = ch0 + cc;
        __syncthreads();   // prior chunk's ds_reads done
        {
            // linear memcpy: wave w stages bytes [w*2KB, w*2KB+2KB) of each array
            const f16* kg = kfb + (size_t)ch * 4096 + w * 1024 + lane * 8;
            const f16* vg = vfb + (size_t)ch * 4096 + w * 1024 + lane * 8;
            glds16(kg, kls + w * 1024);
            glds16(kg + 512, kls + w * 1024 + 512);
            glds16(vg, vls + w * 1024);
            glds16(vg + 512, vls + w * 1024 + 512);
        }
        __syncthreads();   // vmcnt drained: chunk visible

        f16x8 kf[8];
        f16x4 vf[16];
#pragma unroll
        for (int f = 0; f < 8; ++f) kf[f] = *(const f16x8*)(kls + lane * 8 + f * 512);
#pragma unroll
        for (int f = 0; f < 16; ++f) vf[f] = *(const f16x4*)(vls + lane * 4 + f * 256);

#pragma unroll
        for (int i = 0; i < 2; ++i) {
            f32x4 s[4];
#pragma unroll
            for (int jn = 0; jn < 4; ++jn) {
                s[jn] = __builtin_amdgcn_mfma_f32_16x16x32_f16(kf[jn * 2], qf[i][0], z, 0, 0, 0);
                s[jn] = __builtin_amdgcn_mfma_f32_16x16x32_f16(kf[jn * 2 + 1], qf[i][1], s[jn], 0, 0, 0);
            }
#pragma unroll
            for (int jn = 0; jn < 4; ++jn) {
                f16x4 pf;
#pragma unroll
                for (int r = 0; r < 4; ++r)
                    pf[r] = (f16)__builtin_amdgcn_exp2f(fmaf(s[jn][r], SC, -8.0f));
                accl[i] = __builtin_amdgcn_mfma_f32_16x16x16f16(ones, pf, accl[i], 0, 0, 0);
#pragma unroll
                for (int jd = 0; jd < 4; ++jd)
                    acc[jd][i] = __builtin_amdgcn_mfma_f32_16x16x16f16(vf[jd * 4 + jn], pf, acc[jd][i], 0, 0, 0);
            }
        }
    }

    // denominators (f32)
    if (lane < 16) {
#pragma unroll
        for (int i = 0; i < 2; ++i)
            lsb[((size_t)(half * 32 + bh)) * SEQ + row0 + i * 16 + lane] = accl[i][0];
    }
    // numerator: O^T regs -> wave-private LDS transpose -> coalesced f16 store
#pragma unroll
    for (int i = 0; i < 2; ++i)
#pragma unroll
        for (int jd = 0; jd < 4; ++jd)
#pragma unroll
            for (int r = 0; r < 4; ++r)
                ot[w][i * 16 + c][jd * 16 + 4 * g + r] = (f16)acc[jd][i][r];
    f16* aofH = half ? aof1 : aof0;
    const int tr = lane >> 1, hf = lane & 1;
    f16* aob = aofH + (size_t)(b * SEQ + row0 + tr) * HIDDEN + h * HEAD_DIM + hf * 32;
#pragma unroll
    for (int q = 0; q < 4; ++q)
        *(f16x8*)(aob + q * 8) = *(const f16x8*)(&ot[w][tr][hf * 32 + q * 8]);
}

// ---------------------------------------------------------------------------
// combine: aof0 = (aof0 + aof1) / (l0 + l1), 8 dims/thread
// ---------------------------------------------------------------------------
__global__ __launch_bounds__(256) void combine_kernel(f16* __restrict__ a0,
                                                      const f16* __restrict__ a1,
                                                      const float* __restrict__ lsb) {
    const int idx = blockIdx.x * 256 + threadIdx.x;   // < TOKENS*128
    const int part = idx & 127;
    const int tok = idx >> 7;
    const int h = part >> 3, d8 = (part & 7) * 8;
    const int b = tok >> 11, s = tok & 2047;
    const size_t li = (size_t)(b * HEADS + h) * SEQ + s;
    const float inv = 1.0f / (lsb[li] + lsb[32 * SEQ + li]);
    const size_t off = (size_t)tok * HIDDEN + h * HEAD_DIM + d8;
    const f16x8 u = *(const f16x8*)(a0 + off);
    const f16x8 v = *(const f16x8*)(a1 + off);
    f16x8 o;
#pragma unroll
    for (int q = 0; q < 8; ++q) o[q] = (f16)(((float)u[q] + (float)v[q]) * inv);
    *(f16x8*)(a0 + off) = o;
}

// ---------------------------------------------------------------------------
// launch
// ---------------------------------------------------------------------------
extern "C" void kernel_launch(void* const* d_in, const int* in_sizes, int n_in,
                              void* d_out, int out_size, void* d_ws, size_t ws_size,
                              hipStream_t stream) {
    const float* x   = (const float*)d_in[0];
    const float* W_q = (const float*)d_in[1];
    const float* W_k = (const float*)d_in[2];
    const float* W_v = (const float*)d_in[3];
    const float* W_o = (const float*)d_in[4];
    const float* rW1 = (const float*)d_in[5];
    const float* rb1 = (const float*)d_in[6];
    const float* rW2 = (const float*)d_in[7];
    const float* rb2 = (const float*)d_in[8];
    float* out = (float*)d_out;

    const size_t MAT = (size_t)TOKENS * HIDDEN;   // 4M
    const size_t WSZ = (size_t)HIDDEN * HIDDEN;   // 1M
    f16* x16  = (f16*)d_ws;
    f16* wqkv = x16 + MAT;            // [3072][1024]; wot contiguous after
    f16* wot  = wqkv + 3 * WSZ;
    f16* qkv  = wot + WSZ;            // [4096][3072]
    f16* kfr  = qkv + 3 * MAT;
    f16* vfr  = kfr + MAT;
    f16* aof0 = vfr + MAT;
    f16* aof1 = aof0 + MAT;
    f16* w1h  = aof1 + MAT;           // [128][1024]
    f16* w1l  = w1h + POS_DIM * HIDDEN;
    float* raw    = (float*)(w1l + POS_DIM * HIDDEN);
    float* pos    = raw + TOKENS;
    float* costab = pos + TOKENS;
    float* sintab = costab + TOKENS * 32;
    float* lsb    = sintab + TOKENS * 32;   // [2][32][2048]

    cast_x_kernel<<<MAT / 2048, 256, 0, stream>>>(x, x16);
    cast_wt4_kernel<<<dim3(32, 32, 4), 256, 0, stream>>>(W_q, W_k, W_v, W_o, wqkv);
    cast_w1t_kernel<<<dim3(4, 32), 256, 0, stream>>>(rW1, w1h, w1l);

    gemm_gll<<<dim3(24, 32), 256, 0, stream>>>(x16, wqkv, qkv, nullptr, 3072, 1);

    repo_mfma<<<64, 256, 0, stream>>>(x, w1h, w1l, rb1, rW2, rb2, raw);
    repo_cumsum_kernel<<<BATCH, 256, 0, stream>>>(raw, pos);
    sctab_kernel<<<TOKENS * 32 / 256, 256, 0, stream>>>(pos, costab, sintab);

    packkv_kernel<<<dim3(SEQ / 64, HEADS, BATCH), 256, 0, stream>>>(qkv, costab, sintab, kfr, vfr);

    attn_f16<<<dim3(SEQ / 128, HEADS, BATCH * 2), 256, 0, stream>>>(qkv, kfr, vfr, aof0, aof1, lsb);
    combine_kernel<<<TOKENS * 128 / 256, 256, 0, stream>>>(aof0, aof1, lsb);

    gemm_gll<<<dim3(8, 32), 256, 0, stream>>>(aof0, wot, nullptr, out, 1024, 0);
}